// Round 2
// baseline (759.251 us; speedup 1.0000x reference)
//
#include <hip/hip_runtime.h>

// MemoryBank: B=1024 x N=500000, D=128, top-8 cosine, gather values.
// R2: score_select restructured for 4x LDS-read reuse (wave = 64 queries x 16 keys,
//     B-frags in regs => 1 ds_read_b128 : 4 MFMA) + XOR-swizzled ktile (no bank
//     conflicts, no padding). Candidate lists live in block-private global ws at
//     final layout (4 waves share queries; updates rare ~2.7/query/chunk).
// ws: [cscore 8MB][cidx 8MB][qh 256KB][kh 128MB] ≈ 144.3MB

#define DIM 128
#define TOPK 8
#define THR0 0.30f
#define NCH 64     // key chunks (grid.y); grid = 4 x 64 = 256 blocks = 1/CU
#define QPB 256    // queries per block
#define SLOTS 32   // cand slots per (query,chunk) = 4 key-slices x 8
#define NCAND 24   // fp64-rescored candidates per query

typedef _Float16 half8 __attribute__((ext_vector_type(8)));
typedef _Float16 half4v __attribute__((ext_vector_type(4)));
typedef float f32x4 __attribute__((ext_vector_type(4)));

// ---------- K0: L2-normalize rows of [rows x 128] fp32 -> fp16 (float4 loads) ----------
__global__ __launch_bounds__(256) void norm_rows_kernel(const float* __restrict__ in,
                                                        _Float16* __restrict__ outh,
                                                        int rows) {
  int row = blockIdx.x * 8 + (threadIdx.x >> 5);
  int l = threadIdx.x & 31;
  if (row >= rows) return;
  float4 v = *(const float4*)(in + (size_t)row * DIM + l * 4);
  float ss = v.x * v.x + v.y * v.y + v.z * v.z + v.w * v.w;
#pragma unroll
  for (int off = 16; off; off >>= 1) ss += __shfl_xor(ss, off);  // stays in 32-lane half
  float inv = 1.0f / fmaxf(sqrtf(ss), 1e-12f);
  half4v o;
  o.x = (_Float16)(v.x * inv);
  o.y = (_Float16)(v.y * inv);
  o.z = (_Float16)(v.z * inv);
  o.w = (_Float16)(v.w * inv);
  *(half4v*)(outh + (size_t)row * DIM + l * 4) = o;
}

// ---------- K1: fp16 MFMA scoring + threshold-gated per-(query,chunk,slice) top-8 ----------
// Block 1024 thr = 16 waves. Wave w: key-slice ks=w&3 (16 keys of 64-key tile),
// query-group qgrp=w>>2 (64 queries as 4 16-col tiles). B-frags (16) in regs;
// each A-frag ds_read_b128 feeds 4 MFMAs. ktile XOR-swizzled: logical segment s of
// row r stored at s^(r&15) -> conflict-free reads (phys = (quad+4t)^col) and stores.
__global__ __launch_bounds__(1024, 4) void score_select_kernel(
    const _Float16* __restrict__ qh, const _Float16* __restrict__ kh,
    float* cscore, int* cidx, int N, int iters) {
  __shared__ _Float16 ktile[2][64 * 128];  // 2 x 16KB, swizzled, no pad
  __shared__ float thrL[1024];             // per (ks*256 + local query)

  const int tid = threadIdx.x;
  const int lane = tid & 63;
  const int w = tid >> 6;
  const int col = lane & 15;
  const int quad = lane >> 4;
  const int ks = w & 3;
  const int qgrp = w >> 2;
  const int qg = blockIdx.x;
  const int chunk = blockIdx.y;
  const long chunk_base = (long)chunk * iters * 64;

  // init this block's private candidate region (ws is poisoned每 call) + thresholds
  for (int e = tid; e < QPB * SLOTS; e += 1024) {
    size_t o = ((size_t)(qg * QPB + (e >> 5))) * (NCH * SLOTS) + (size_t)chunk * SLOTS + (e & 31);
    cscore[o] = -1e30f;
    cidx[o] = 0;
  }
  thrL[tid & 1023] = THR0;

  // B fragments: 4 query-tiles x 4 k-slices, loaded once (64 VGPRs)
  half8 bf[4][4];
  {
    const _Float16* qbase = qh + ((size_t)qg * QPB + qgrp * 64 + col) * DIM + quad * 8;
#pragma unroll
    for (int qt = 0; qt < 4; qt++)
#pragma unroll
      for (int t = 0; t < 4; t++)
        bf[qt][t] = *(const half8*)(qbase + qt * 16 * DIM + t * 32);
  }

  // staging: thread t -> 16B unit (row srow, logical segment scol), swizzled store
  const int srow = tid >> 4;
  const int scol = tid & 15;
  const int st_off = srow * 128 + ((scol ^ (srow & 15)) * 8);

  float4 staged;
  {
    long key = chunk_base + srow;
    if (key < (long)N)
      staged = *(const float4*)(kh + key * (size_t)DIM + scol * 8);
    else
      staged.x = staged.y = staged.z = staged.w = 0.f;
  }

  float thr_c[4] = {THR0, THR0, THR0, THR0};

  for (int it = 0; it < iters; ++it) {
    *(float4*)(&ktile[it & 1][st_off]) = staged;
    __syncthreads();
    if (it + 1 < iters) {  // prefetch next tile after barrier (latency hidden by MFMA)
      long key = chunk_base + (long)(it + 1) * 64 + srow;
      if (key < (long)N)
        staged = *(const float4*)(kh + key * (size_t)DIM + scol * 8);
      else
        staged.x = staged.y = staged.z = staged.w = 0.f;
    }
    const _Float16* kt = ktile[it & 1];
    const int arow = (ks * 16 + col) * 128;

    f32x4 acc[4];
#pragma unroll
    for (int qt = 0; qt < 4; qt++) acc[qt] = (f32x4){0.f, 0.f, 0.f, 0.f};
#pragma unroll
    for (int t = 0; t < 4; t++) {
      half8 af = *(const half8*)(kt + arow + (((quad + 4 * t) ^ col) * 8));
#pragma unroll
      for (int qt = 0; qt < 4; qt++)
        acc[qt] = __builtin_amdgcn_mfma_f32_16x16x32_f16(af, bf[qt][t], acc[qt], 0, 0, 0);
    }

    const long keyb = chunk_base + (long)it * 64 + ks * 16;
#pragma unroll
    for (int qt = 0; qt < 4; qt++) {
      float mx = fmaxf(fmaxf(acc[qt][0], acc[qt][1]), fmaxf(acc[qt][2], acc[qt][3]));
      if (__any(mx > thr_c[qt])) {  // rare
#pragma unroll
        for (int r = 0; r < 4; ++r) {
          float av = acc[qt][r];
          unsigned long long m = __ballot(av > thr_c[qt]);
          while (m) {
            int src = __ffsll(m) - 1;
            m &= m - 1;
            float sc = __shfl(av, src);
            int qq = qgrp * 64 + qt * 16 + (src & 15);
            long kk = keyb + (src >> 4) * 4 + r;
            if (lane == 0 && kk < (long)N) {
              size_t base = ((size_t)(qg * QPB + qq)) * (NCH * SLOTS) + (size_t)chunk * SLOTS + ks * 8;
              float* Ls = cscore + base;
              int* Li = cidx + base;
              float lv[8];
#pragma unroll
              for (int s2 = 0; s2 < 8; s2++) lv[s2] = Ls[s2];
              float mn = lv[0];
              int ms = 0;
#pragma unroll
              for (int s2 = 1; s2 < 8; s2++)
                if (lv[s2] < mn) { mn = lv[s2]; ms = s2; }
              if (sc > mn) {
                Ls[ms] = sc;
                Li[ms] = (int)kk;
                lv[ms] = sc;
                float nm = lv[0];
#pragma unroll
                for (int s2 = 1; s2 < 8; s2++) nm = fminf(nm, lv[s2]);
                thrL[ks * 256 + qq] = fmaxf(THR0, nm);
              }
            }
          }
        }
        thr_c[qt] = thrL[ks * 256 + qgrp * 64 + qt * 16 + col];
      }
    }
  }
}

// ---------- K2: merge candidates, fp64 rescore, final top-8, gather values ----------
__global__ __launch_bounds__(64) void merge_rescore_kernel(
    const float* __restrict__ Q, const float* __restrict__ Kf, const float* __restrict__ V,
    const float* __restrict__ cscore, const int* __restrict__ cidx,
    float* __restrict__ out, int N) {
  const int q = blockIdx.x;
  const int lane = threadIdx.x;
  const int E = NCH * SLOTS;  // 2048 candidate slots per query
  float s[32];
  int ii[32];
#pragma unroll
  for (int i = 0; i < 32; i++) {
    size_t o = (size_t)q * E + i * 64 + lane;
    s[i] = cscore[o];
    ii[i] = cidx[o];
  }
  __shared__ int topI[NCAND];
  __shared__ double simsL[NCAND];
  unsigned consumed = 0;
  for (int t = 0; t < NCAND; t++) {
    float bv = -3e38f;
    int bid = 0x7fffffff;
    int bpos = -1;
#pragma unroll
    for (int i = 0; i < 32; i++) {
      float v = ((consumed >> i) & 1) ? -3e38f : s[i];
      if (v > bv || (v == bv && ii[i] < bid)) { bv = v; bid = ii[i]; bpos = i; }
    }
    float myv = bv;
    int myi = bid;
#pragma unroll
    for (int off = 32; off; off >>= 1) {
      float ov = __shfl_xor(bv, off);
      int oi = __shfl_xor(bid, off);
      if (ov > bv || (ov == bv && oi < bid)) { bv = ov; bid = oi; }
    }
    if (bv <= -1e29f) {  // only sentinel pads left
      if (lane == 0)
        for (int z = t; z < NCAND; z++) topI[z] = -1;
      break;
    }
    if (bpos >= 0 && myv == bv && myi == bid) consumed |= 1u << bpos;
    if (lane == 0) topI[t] = bid;
  }
  __syncthreads();

  // fp64 rescore from RAW fp32 inputs (matches np fp64 reference ranking)
  float q0 = Q[(size_t)q * DIM + lane];
  float q1 = Q[(size_t)q * DIM + 64 + lane];
  double dq = (double)q0 * q0 + (double)q1 * q1;
#pragma unroll
  for (int off = 32; off; off >>= 1) dq += __shfl_xor(dq, off);
  double qn = fmax(sqrt(dq), 1e-12);
  for (int c = 0; c < NCAND; ++c) {
    int id = topI[c];
    int idc = id < 0 ? 0 : id;
    float kx = Kf[(size_t)idc * DIM + lane];
    float ky = Kf[(size_t)idc * DIM + 64 + lane];
    double dot = (double)q0 * kx + (double)q1 * ky;
    double ksq = (double)kx * kx + (double)ky * ky;
#pragma unroll
    for (int off = 32; off; off >>= 1) {
      dot += __shfl_xor(dot, off);
      ksq += __shfl_xor(ksq, off);
    }
    double sim = dot / (qn * fmax(sqrt(ksq), 1e-12));
    if (lane == 0) simsL[c] = (id >= 0) ? sim : -1e300;
  }
  __syncthreads();

  // final top-8: value desc, index asc (jax top_k tie-break), gather values
  unsigned used = 0;
  for (int j = 0; j < TOPK; j++) {
    double bv = -1e301;
    int bc = -1;
    int bid = 0x7fffffff;
    for (int c = 0; c < NCAND; c++) {
      if ((used >> c) & 1) continue;
      int id = topI[c];
      if (id < 0) continue;
      double v = simsL[c];
      if (v > bv || (v == bv && id < bid)) { bv = v; bid = id; bc = c; }
    }
    int row = 0;
    if (bc >= 0) {
      used |= 1u << bc;
      row = topI[bc];
    }
    out[((size_t)q * TOPK + j) * DIM + lane] = V[(size_t)row * DIM + lane];
    out[((size_t)q * TOPK + j) * DIM + 64 + lane] = V[(size_t)row * DIM + 64 + lane];
  }
}

extern "C" void kernel_launch(void* const* d_in, const int* in_sizes, int n_in,
                              void* d_out, int out_size, void* d_ws, size_t ws_size,
                              hipStream_t stream) {
  const float* Q = (const float*)d_in[0];
  const float* Kf = (const float*)d_in[1];
  const float* V = (const float*)d_in[2];
  float* out = (float*)d_out;
  const int B = in_sizes[0] / DIM;  // 1024
  const int N = in_sizes[1] / DIM;  // 500000

  char* ws = (char*)d_ws;
  size_t cand_elems = (size_t)B * NCH * SLOTS;  // 2,097,152
  float* cscore = (float*)ws;
  int* cidx = (int*)(ws + cand_elems * 4);
  _Float16* qh = (_Float16*)(ws + cand_elems * 8);
  _Float16* kh = (_Float16*)(ws + cand_elems * 8 + (size_t)B * DIM * 2);
  // ws use: 16MB + 256KB + N*256B (~144.3MB)

  int iters = (N + NCH * 64 - 1) / (NCH * 64);  // 123 tiles of 64 keys per chunk

  norm_rows_kernel<<<dim3((B + 7) / 8), 256, 0, stream>>>(Q, qh, B);
  norm_rows_kernel<<<dim3((N + 7) / 8), 256, 0, stream>>>(Kf, kh, N);
  score_select_kernel<<<dim3(B / QPB, NCH), 1024, 0, stream>>>(qh, kh, cscore, cidx, N, iters);
  merge_rescore_kernel<<<dim3(B), 64, 0, stream>>>(Q, Kf, V, cscore, cidx, out, N);
}